// Round 14
// baseline (6051.985 us; speedup 1.0000x reference)
//
#include <hip/hip_runtime.h>

// Echo-state RNN, B=32, T=2048, NH=512.  W_hh ~90% exact zeros.
// One workgroup (CU) per batch; thread p owns row perm2[p]. Cost model
// (fits r1-r13): step ~= gather-instrs x 2.6cyc + ~1150cyc tail. Greedy
// coloring needs ~2*Delta colors (measured cntw~96, 3 rounds of chain-flip
// Koenig all silently degraded). NEW scheduler: exact Delta-edge-coloring
// via repeated MAX-DEGREE-SATURATING MATCHINGS (Koenig's proof done the
// simple way): per color, Kuhn augmenting paths saturate all current-max-
// degree lanes AND banks, greedy-extend, commit, max degree drops by 1 ->
// exactly Delta colors (~66..78/wave vs 96). All failure modes degrade to
// leftover-dump (= today's schedule quality) -- never wrong results.
// esn_steps = round-13 kernel verbatim (best measured: 2380us).

#define NH   512
#define TT   2048
#define BB   32
#define PAD  96
#define PIN  80
#define NONE_ 0xFF

// ---------------------------------------------------------------------------
// A: nnz per row (wave-per-row ballot count)
// ---------------------------------------------------------------------------
__global__ __launch_bounds__(512) void count_nnz(
    const float* __restrict__ Whh, int* __restrict__ nnz) {
  const int wib  = threadIdx.x >> 6;
  const int lane = threadIdx.x & 63;
  const int row  = blockIdx.x * 8 + wib;
  const float* wrow = Whh + (size_t)row * NH;
  int cnt = 0;
  for (int c = 0; c < NH / 64; ++c)
    cnt += __popcll(__ballot(wrow[c * 64 + lane] != 0.0f));
  if (lane == 0) nnz[row] = cnt;
}

// ---------------------------------------------------------------------------
// B: rank rows by nnz descending (stable). perm[p] = row at sorted pos p.
// ---------------------------------------------------------------------------
__global__ __launch_bounds__(512) void sort_rows(
    const int* __restrict__ nnz, int* __restrict__ perm) {
  __shared__ int nl[NH];
  const int j = threadIdx.x;
  const int my = nnz[j];
  nl[j] = my;
  __syncthreads();
  int r = 0;
  const int4* p4 = (const int4*)nl;
  for (int i = 0; i < NH / 4; ++i) {
    int4 v = p4[i];
    const int base = i * 4;
    r += (v.x > my) || (v.x == my && base + 0 < j);
    r += (v.y > my) || (v.y == my && base + 1 < j);
    r += (v.z > my) || (v.z == my && base + 2 < j);
    r += (v.w > my) || (v.w == my && base + 3 < j);
  }
  perm[r] = j;
}

// ---------------------------------------------------------------------------
// Kuhn augmenting path from an unmatched lane (bank-side symmetric).
// bm*[v] = adjacency bitmask (bit set iff multiplicity > 0). Flipping the
// found path newly-matches only the two endpoints; interior stays matched.
// ---------------------------------------------------------------------------
__device__ bool kuhn_L(int l0, const unsigned* bmL,
                       signed char* mtL, signed char* mtB) {
  unsigned visited = 0; int sp = 0;
  unsigned char stk[33], chb[33]; unsigned cnd[33];
  stk[0] = (unsigned char)l0; cnd[0] = bmL[l0];
  while (sp >= 0) {
    unsigned m = cnd[sp] & ~visited;
    if (!m) { --sp; continue; }
    int b = __ffs(m) - 1;
    cnd[sp] &= ~(1u << b); visited |= 1u << b;
    chb[sp] = (unsigned char)b;
    if (mtB[b] < 0) {
      for (int i = sp; i >= 0; --i) {
        mtB[chb[i]] = (signed char)stk[i];
        mtL[stk[i]] = (signed char)chb[i];
      }
      return true;
    }
    stk[sp + 1] = (unsigned char)mtB[b];
    cnd[sp + 1] = bmL[mtB[b]];
    ++sp;
  }
  return false;
}
__device__ bool kuhn_B(int b0, const unsigned* bmB,
                       signed char* mtL, signed char* mtB) {
  unsigned visited = 0; int sp = 0;
  unsigned char stk[33], chl[33]; unsigned cnd[33];
  stk[0] = (unsigned char)b0; cnd[0] = bmB[b0];
  while (sp >= 0) {
    unsigned m = cnd[sp] & ~visited;
    if (!m) { --sp; continue; }
    int l = __ffs(m) - 1;
    cnd[sp] &= ~(1u << l); visited |= 1u << l;
    chl[sp] = (unsigned char)l;
    if (mtL[l] < 0) {
      for (int i = sp; i >= 0; --i) {
        mtL[chl[i]] = (signed char)stk[i];
        mtB[stk[i]] = (signed char)chl[i];
      }
      return true;
    }
    stk[sp + 1] = (unsigned char)mtL[l];
    cnd[sp + 1] = bmB[mtL[l]];
    ++sp;
  }
  return false;
}

// ---------------------------------------------------------------------------
// C: partition + matching-based Delta-edge-coloring per (wave, half).
// Block = wave g (grid 8, 128 threads = 2 waves; worker tid 0 -> half 0,
// worker tid 64 -> half 1, running in PARALLEL waves).
// ---------------------------------------------------------------------------
__global__ __launch_bounds__(128) void build_match(
    const float* __restrict__ Whh, const int* __restrict__ perm,
    int* __restrict__ perm2, float* __restrict__ vals,
    unsigned* __restrict__ offs, int* __restrict__ cntw) {
  __shared__ unsigned short occ0[64][32];    // presence bits, original order
  __shared__ unsigned short occ[64][32];     // by new lane order
  __shared__ unsigned char  mult[2][32][32]; // multiplicity per (lane,bank)
  __shared__ unsigned bmL[2][32], bmB[2][32];
  __shared__ short degL[2][32], degB[2][32];
  __shared__ signed char mtL[2][32], mtB[2][32];
  __shared__ unsigned char sb[64][PAD];      // slot -> bank (NONE_)
  __shared__ unsigned char lorder[64], asg[64];
  __shared__ int blc[2][32];
  __shared__ int cmax[2];

  const int tid = threadIdx.x;
  const int g   = blockIdx.x;

  // -- phase 1: occ0 via coalesced loads + ballot transpose (wave 0) --
  if (tid < 64) {
    for (int r = 0; r < 64; ++r) {
      const int rw = perm[g * 64 + r];
      const float* wr = Whh + (size_t)rw * NH;
      unsigned m16 = 0;
      for (int c = 0; c < 8; ++c) {
        unsigned long long bal = __ballot(wr[c * 64 + tid] != 0.0f);
        if (tid < 32) {
          m16 |= ((unsigned)((bal >> tid) & 1ull)) << (2 * c);
          m16 |= ((unsigned)((bal >> (tid + 32)) & 1ull)) << (2 * c + 1);
        }
      }
      if (tid < 32) occ0[r][tid] = (unsigned short)m16;
    }
  }
  __syncthreads();

  // -- phase 2: bank-balancing partition of 64 rows into 2 halves (tid 0) --
  if (tid == 0) {
    int cnt0 = 0, cnt1 = 0;
    for (int b = 0; b < 32; ++b) { blc[0][b] = 0; blc[1][b] = 0; }
    for (int r = 0; r < 64; ++r) {
      int m0 = 0, m1 = 0;
      for (int b = 0; b < 32; ++b) {
        int c = __popc((unsigned)occ0[r][b]);
        int t0 = blc[0][b] + c; if (t0 > m0) m0 = t0;
        int t1 = blc[1][b] + c; if (t1 > m1) m1 = t1;
      }
      int h;
      if (cnt0 >= 32) h = 1;
      else if (cnt1 >= 32) h = 0;
      else h = (m1 < m0) ? 1 : 0;
      asg[r] = (unsigned char)h;
      if (h == 0) ++cnt0; else ++cnt1;
      for (int b = 0; b < 32; ++b) blc[h][b] += __popc((unsigned)occ0[r][b]);
    }
    int i0 = 0, i1 = 32;
    for (int r = 0; r < 64; ++r) {
      if (asg[r] == 0) lorder[i0++] = (unsigned char)r;
      else             lorder[i1++] = (unsigned char)r;
    }
    cmax[0] = 0; cmax[1] = 0;
  }
  __syncthreads();

  // -- phase 3: reorder + init matching state (wave 0, tid<64) --
  if (tid < 64) {
    const int hl = tid >> 5, li = tid & 31;
    const int lo = lorder[tid];
    perm2[g * 64 + tid] = perm[g * 64 + lo];
    int dl = 0; unsigned ml = 0;
    for (int b = 0; b < 32; ++b) {
      unsigned short v = occ0[lo][b];
      occ[tid][b] = v;
      int c = __popc((unsigned)v);
      mult[hl][li][b] = (unsigned char)c;
      dl += c;
      if (c) ml |= 1u << b;
    }
    degL[hl][li] = (short)dl;
    bmL[hl][li]  = ml;
    for (int c = 0; c < PAD; ++c) sb[tid][c] = NONE_;
  }
  __syncthreads();
  if (tid < 64) {                            // bank-side masks/degrees
    const int hl = tid >> 5, bk = tid & 31;
    int db = 0; unsigned mb = 0;
    for (int l = 0; l < 32; ++l) {
      int c = mult[hl][l][bk];
      db += c;
      if (c) mb |= 1u << l;
    }
    degB[hl][bk] = (short)db;
    bmB[hl][bk]  = mb;
  }
  __syncthreads();

  // -- phase 4: coloring workers (tid 0 -> half 0, tid 64 -> half 1) --
  if ((tid & 63) == 0) {
    const int hl = tid >> 6;
    int edges = 0;
    for (int l = 0; l < 32; ++l) edges += degL[hl][l];
    int c = 0;
    while (edges > 0 && c < PAD) {
      int D = 0;
      for (int v = 0; v < 32; ++v) {
        if (degL[hl][v] > D) D = degL[hl][v];
        if (degB[hl][v] > D) D = degB[hl][v];
      }
      for (int v = 0; v < 32; ++v) { mtL[hl][v] = -1; mtB[hl][v] = -1; }
      // saturate all current-max-degree lanes, then banks
      for (int l = 0; l < 32; ++l)
        if (degL[hl][l] == D && mtL[hl][l] < 0)
          kuhn_L(l, bmL[hl], mtL[hl], mtB[hl]);
      for (int b = 0; b < 32; ++b)
        if (degB[hl][b] == D && mtB[hl][b] < 0)
          kuhn_B(b, bmB[hl], mtL[hl], mtB[hl]);
      // greedy maximal extension (consumes edges faster, free)
      for (int l = 0; l < 32; ++l) {
        if (mtL[hl][l] >= 0) continue;
        unsigned m = bmL[hl][l];
        while (m) {
          int b = __ffs(m) - 1; m &= m - 1u;
          if (mtB[hl][b] < 0) {
            mtL[hl][l] = (signed char)b; mtB[hl][b] = (signed char)l;
            break;
          }
        }
      }
      // commit color c
      bool any = false;
      for (int l = 0; l < 32; ++l) {
        int b = mtL[hl][l];
        if (b < 0) continue;
        sb[hl * 32 + l][c] = (unsigned char)b;
        if (--mult[hl][l][b] == 0) {
          bmL[hl][l] &= ~(1u << b);
          bmB[hl][b] &= ~(1u << l);
        }
        --degL[hl][l]; --degB[hl][b]; --edges;
        any = true;
      }
      if (!any) break;                       // safety (cannot normally occur)
      ++c;
    }
    // fallback dump: place any leftovers at free lane slots (conflicts ok)
    if (edges > 0) {
      for (int l = 0; l < 32; ++l) {
        const int gl = hl * 32 + l;
        for (int b = 0; b < 32; ++b) {
          while (mult[hl][l][b] > 0) {
            int s = -1;
            for (int cc = 0; cc < PAD && s < 0; ++cc)
              if (sb[gl][cc] == NONE_) s = cc;
            sb[gl][s] = (unsigned char)b;
            --mult[hl][l][b];
            if (s + 1 > c) c = s + 1;
          }
        }
      }
    }
    cmax[hl] = c;
  }
  __syncthreads();
  if (tid == 0)
    cntw[g] = cmax[0] > cmax[1] ? cmax[0] : cmax[1];

  // -- phase 5: write schedule (entry-major by new position) --
  if (tid < 64) {
    const int p2 = g * 64 + tid;
    const float* wr2 = Whh + (size_t)perm2[p2] * NH;
    for (int c = 0; c < PAD; ++c) {
      int b = sb[tid][c];
      float v = 0.f; unsigned col = 0u;
      if (b != NONE_) {
        unsigned m16 = (unsigned)occ[tid][b];
        int m = __ffs(m16) - 1;
        occ[tid][b] = (unsigned short)(m16 & (m16 - 1u));
        col = (unsigned)(b + 32 * m);
        v = wr2[col];
      }
      vals[c * NH + p2] = v;
      offs[c * NH + p2] = col;
    }
  }
}

// ---------------------------------------------------------------------------
// DPP wave-64 sum reduction on the VALU pipe; lane 63 ends with the full sum.
// ---------------------------------------------------------------------------
template <int CTRL, int RM>
__device__ __forceinline__ float dppadd(float v) {
  int t = __builtin_amdgcn_update_dpp(0, __float_as_int(v), CTRL, RM, 0xF, true);
  return v + __int_as_float(t);
}
__device__ __forceinline__ float wave_sum_lane63(float v) {
  v = dppadd<0xB1,  0xF>(v);
  v = dppadd<0x4E,  0xF>(v);
  v = dppadd<0x141, 0xF>(v);
  v = dppadd<0x140, 0xF>(v);
  v = dppadd<0x142, 0xA>(v);
  v = dppadd<0x143, 0xC>(v);
  return v;
}

// fast tanh: (t-1)/(t+1), t = exp(2x), clamp |x|<=9.
__device__ __forceinline__ float ftanh(float x) {
  float xc = fminf(9.0f, fmaxf(-9.0f, x));
  float t  = __expf(2.0f * xc);
  return (t - 1.0f) * __builtin_amdgcn_rcpf(t + 1.0f);
}

// ---------------------------------------------------------------------------
// Main: one block per batch, 512 threads, 2048 sequential steps (x2 unroll).
// Round-13 kernel verbatim.
// ---------------------------------------------------------------------------
#define GA(T_RD, E) (*(const float*)((const char*)(T_RD) + cidx[E]))

#define ESN_STEP(T_RD, T_WR, RWR, SIDX)                                      \
  {                                                                          \
    float d0 = 0.f, d1 = 0.f, d2 = 0.f, d3 = 0.f;                            \
    _Pragma("unroll")                                                        \
    for (int e = 0; e < PAD; e += 8) {                                       \
      if (e < cw) {                                                          \
        d0 = fmaf(wval[e + 0], GA(T_RD, e + 0), d0);                         \
        d1 = fmaf(wval[e + 1], GA(T_RD, e + 1), d1);                         \
        d2 = fmaf(wval[e + 2], GA(T_RD, e + 2), d2);                         \
        d3 = fmaf(wval[e + 3], GA(T_RD, e + 3), d3);                         \
        d0 = fmaf(wval[e + 4], GA(T_RD, e + 4), d0);                         \
        d1 = fmaf(wval[e + 5], GA(T_RD, e + 5), d1);                         \
        d2 = fmaf(wval[e + 6], GA(T_RD, e + 6), d2);                         \
        d3 = fmaf(wval[e + 7], GA(T_RD, e + 7), d3);                         \
      }                                                                      \
    }                                                                        \
    float dot  = (d0 + d1) + (d2 + d3);                                      \
    float xp   = x_lds[SIDX] * w_ih;                                         \
    float dhdt = ((dot - h) + xp) + z_prev * w_zh;                           \
    float hn   = h + 0.1f * dhdt;                                            \
    float thn  = ftanh(hn);                                                  \
    T_WR[row] = thn;                                                         \
    oh[(SIDX) * NH + row] = hn;                                              \
    float pzs = wave_sum_lane63(thn * w_hz);                                 \
    if (lane == 63) red[RWR][wid] = pzs;                                     \
    asm volatile("s_waitcnt lgkmcnt(0)\n\ts_barrier" ::: "memory");          \
    float4 r0 = *(const float4*)&red[RWR][0];                                \
    float4 r1 = *(const float4*)&red[RWR][4];                                \
    float z = ((r0.x + r0.y) + (r0.z + r0.w)) + ((r1.x + r1.y) + (r1.z + r1.w)); \
    if (p == 0) oz[SIDX] = z;                                                \
    z_prev = z; h = hn;                                                      \
  }

__global__ __launch_bounds__(512, 2) void esn_steps(
    const float* __restrict__ x,   const float* __restrict__ h0,
    const float* __restrict__ Wih, const float* __restrict__ Whz,
    const float* __restrict__ Wzh, const float* __restrict__ vals,
    const unsigned* __restrict__ offs, const int* __restrict__ perm2,
    const int* __restrict__ cntw, float* __restrict__ out) {
  __shared__ float t_lds[2][NH];              // tanh(h), double-buffered
  __shared__ float x_lds[TT];                 // this batch's input row
  __shared__ __align__(16) float red[2][8];   // cross-wave partials for z

  const int p    = threadIdx.x;               // position owned
  const int b    = blockIdx.x;
  const int lane = p & 63;
  const int wid  = p >> 6;
  const int row  = perm2[p];                  // actual hidden unit

  float* t0 = t_lds[0];
  float* t1 = t_lds[1];

  for (int i = p; i < TT; i += NH) x_lds[i] = x[(size_t)b * TT + i];

  int cw = __builtin_amdgcn_readfirstlane((cntw[wid] + 7) & ~7);

  float    wval[PAD];
  unsigned cidx[PAD];
  #pragma unroll
  for (int e = 0; e < PAD; ++e) {
    wval[e] = vals[e * NH + p];
    cidx[e] = offs[e * NH + p] * 4u;
  }
  #pragma unroll
  for (int e = 0; e < PIN; ++e)
    asm volatile("" : "+v"(wval[e]), "+v"(cidx[e]));

  const float w_ih = Wih[row];
  const float w_hz = Whz[row];
  const float w_zh = Wzh[row];
  float h = h0[(size_t)b * NH + row];

  float* oz = out + (size_t)b * TT;                        // z region [B,T,1]
  float* oh = out + (size_t)BB * TT + (size_t)b * TT * NH; // h region [B,T,NH]

  float th0 = ftanh(h);
  t0[row] = th0;
  float pz = wave_sum_lane63(th0 * w_hz);
  if (lane == 63) red[0][wid] = pz;
  __syncthreads();
  float4 i0 = *(const float4*)&red[0][0];
  float4 i1 = *(const float4*)&red[0][4];
  float z_prev = ((i0.x + i0.y) + (i0.z + i0.w)) + ((i1.x + i1.y) + (i1.z + i1.w));

  for (int s = 0; s < TT; s += 2) {
    ESN_STEP(t0, t1, 1, s);
    ESN_STEP(t1, t0, 0, s + 1);
  }
}

// ---------------------------------------------------------------------------
extern "C" void kernel_launch(void* const* d_in, const int* in_sizes, int n_in,
                              void* d_out, int out_size, void* d_ws,
                              size_t ws_size, hipStream_t stream) {
  const float* x   = (const float*)d_in[0];
  const float* h0  = (const float*)d_in[1];
  const float* Wih = (const float*)d_in[2];
  const float* Whh = (const float*)d_in[3];
  const float* Whz = (const float*)d_in[4];
  const float* Wzh = (const float*)d_in[5];
  float* out = (float*)d_out;

  float*    vals  = (float*)d_ws;                    // PAD*NH f32 = 192 KB
  unsigned* offs  = (unsigned*)(vals + PAD * NH);    // PAD*NH u32 = 192 KB
  int*      nnz   = (int*)(offs + PAD * NH);         // NH
  int*      perm  = nnz + NH;                        // NH
  int*      perm2 = perm + NH;                       // NH
  int*      cntw  = perm2 + NH;                      // 8

  hipLaunchKernelGGL(count_nnz, dim3(NH / 8), dim3(512), 0, stream, Whh, nnz);
  hipLaunchKernelGGL(sort_rows, dim3(1), dim3(512), 0, stream, nnz, perm);
  hipLaunchKernelGGL(build_match, dim3(8), dim3(128), 0, stream,
                     Whh, perm, perm2, vals, offs, cntw);
  hipLaunchKernelGGL(esn_steps, dim3(BB), dim3(512), 0, stream,
                     x, h0, Wih, Whz, Wzh, vals, offs, perm2, cntw, out);
}

// Round 15
// 2678.886 us; speedup vs baseline: 2.2591x; 2.2591x over previous
//
#include <hip/hip_runtime.h>

// Echo-state RNN, B=32, T=2048, NH=512.  W_hh ~90% exact zeros.
// r14 proved matching-based Delta-edge-coloring gives esn ~2030us (cntw~76
// vs greedy 96) -- but its serial Kuhn worker used runtime-indexed local
// arrays (-> scratch, rule #20) and cost 3959us. This round: WAVE-PARALLEL
// priority matching, same quality target, ~150us:
//  - per color, 32 lanes/half propose banks (preference: banks where the
//    lane has most remaining entries -- register tier masks, lane-rotated);
//  - arbitration atomicMax key = (remaining<<6)|lane: high-degree lanes win
//    (approximates Kuhn's max-degree saturation);
//  - sticky per-color bank locks, 4 rounds, per-lane force backstop.
// Partition (bank-balancing, r13) parallelized via wave shuffle-max.
// esn_steps = round-13 kernel verbatim (best measured).

#define NH   512
#define TT   2048
#define BB   32
#define PAD  96
#define PIN  80

// ---------------------------------------------------------------------------
// A: nnz per row (wave-per-row ballot count)
// ---------------------------------------------------------------------------
__global__ __launch_bounds__(512) void count_nnz(
    const float* __restrict__ Whh, int* __restrict__ nnz) {
  const int wib  = threadIdx.x >> 6;
  const int lane = threadIdx.x & 63;
  const int row  = blockIdx.x * 8 + wib;
  const float* wrow = Whh + (size_t)row * NH;
  int cnt = 0;
  for (int c = 0; c < NH / 64; ++c)
    cnt += __popcll(__ballot(wrow[c * 64 + lane] != 0.0f));
  if (lane == 0) nnz[row] = cnt;
}

// ---------------------------------------------------------------------------
// B: rank rows by nnz descending (stable). perm[p] = row at sorted pos p.
// ---------------------------------------------------------------------------
__global__ __launch_bounds__(512) void sort_rows(
    const int* __restrict__ nnz, int* __restrict__ perm) {
  __shared__ int nl[NH];
  const int j = threadIdx.x;
  const int my = nnz[j];
  nl[j] = my;
  __syncthreads();
  int r = 0;
  const int4* p4 = (const int4*)nl;
  for (int i = 0; i < NH / 4; ++i) {
    int4 v = p4[i];
    const int base = i * 4;
    r += (v.x > my) || (v.x == my && base + 0 < j);
    r += (v.y > my) || (v.y == my && base + 1 < j);
    r += (v.z > my) || (v.z == my && base + 2 < j);
    r += (v.w > my) || (v.w == my && base + 3 < j);
  }
  perm[r] = j;
}

// ---------------------------------------------------------------------------
// C: partition + wave-parallel priority-matching edge coloring.
// ONE block of 512 threads; wave w handles virtual wave w (rows
// perm[w*64 .. w*64+63]); its two half-waves run 32x32 subproblems in
// parallel (claim tables per (wave,half); intra-wave LDS ordering is
// program order, the r5-r8 proven pattern).
// ---------------------------------------------------------------------------
__global__ __launch_bounds__(512) void build_psched(
    const float* __restrict__ Whh, const int* __restrict__ perm,
    int* __restrict__ perm2, float* __restrict__ vals,
    unsigned* __restrict__ offs, int* __restrict__ cntw) {
  __shared__ unsigned short occ[8][64][32];   // presence bits, orig order
  __shared__ unsigned char  lorder[8][64];    // new lane -> orig row index
  __shared__ int   claim[8][2][32];
  __shared__ short bload[8][2][32];
  __shared__ short cnth[8][2];

  const int tid  = threadIdx.x;
  const int w    = tid >> 6;
  const int lane = tid & 63;
  const int hl   = (lane >> 5) & 1;
  const int li   = lane & 31;

  // -- phase 1: occ via coalesced loads + ballot transpose (per wave) --
  for (int r = 0; r < 64; ++r) {
    const int rw = perm[w * 64 + r];
    const float* wr = Whh + (size_t)rw * NH;
    unsigned m16 = 0;
    for (int c = 0; c < 8; ++c) {
      unsigned long long bal = __ballot(wr[c * 64 + lane] != 0.0f);
      if (lane < 32) {
        m16 |= ((unsigned)((bal >> lane) & 1ull)) << (2 * c);
        m16 |= ((unsigned)((bal >> (lane + 32)) & 1ull)) << (2 * c + 1);
      }
    }
    if (lane < 32) occ[w][r][lane] = (unsigned short)m16;
  }
  if (lane < 32) { bload[w][0][lane] = 0; bload[w][1][lane] = 0; }
  if (lane == 0) { cnth[w][0] = 0; cnth[w][1] = 0; }
  __builtin_amdgcn_wave_barrier();

  // -- phase 2: bank-balancing partition, wave-parallel over banks --
  for (int r = 0; r < 64; ++r) {
    int cb = 0, t0 = 0, t1 = 0;
    if (lane < 32) {
      cb = __popc((unsigned)occ[w][r][lane]);
      t0 = bload[w][0][lane] + cb;
      t1 = bload[w][1][lane] + cb;
    }
    int m0 = t0, m1 = t1;
    #pragma unroll
    for (int o = 32; o > 0; o >>= 1) {
      int u0 = __shfl_xor(m0, o), u1 = __shfl_xor(m1, o);
      m0 = u0 > m0 ? u0 : m0;
      m1 = u1 > m1 ? u1 : m1;
    }
    int c0 = cnth[w][0], c1 = cnth[w][1];
    int h;
    if (c0 >= 32) h = 1;
    else if (c1 >= 32) h = 0;
    else h = (m1 < m0) ? 1 : 0;
    if (lane < 32) bload[w][h][lane] = (short)(bload[w][h][lane] + cb);
    if (lane == 0) {
      lorder[w][h * 32 + (h ? c1 : c0)] = (unsigned char)r;
      cnth[w][h] = (short)((h ? c1 : c0) + 1);
    }
    __builtin_amdgcn_wave_barrier();
  }

  // -- phase 3: per-thread state (thread owns the row at its new position) --
  const int o   = lorder[w][lane];
  const int row = perm[w * 64 + o];
  const int p   = w * 64 + lane;
  perm2[p] = row;
  unsigned short* myocc = occ[w][o];
  const float* wrow = Whh + (size_t)row * NH;
  unsigned bmAll = 0, bm2 = 0, bm4 = 0;
  int rem = 0;
  for (int b = 0; b < 32; ++b) {
    int m = __popc((unsigned)myocc[b]);
    rem += m;
    if (m >= 1) bmAll |= 1u << b;
    if (m >= 2) bm2   |= 1u << b;
    if (m >= 4) bm4   |= 1u << b;
  }

  // -- phase 4: priority-matching color loop --
  int c = 0;
  while (__ballot(rem > 0) != 0ull && c < PAD) {
    claim[w][hl][li] = 0;
    __builtin_amdgcn_wave_barrier();
    const int  key   = (rem << 6) | (li + 1);
    const bool force = (PAD - c) <= rem;
    bool placed = false; int myb = 0;
    unsigned excl = 0;

    #pragma unroll
    for (int round = 0; round < 4; ++round) {
      bool want = !placed && rem > 0;
      int b = 0;
      if (want) {
        unsigned cand = bmAll & ~excl;
        unsigned pref = cand & bm4;
        if (!pref) pref = cand & bm2;
        if (!pref) pref = cand;
        if (!pref) { want = false; }
        else {
          unsigned rot = li ? ((pref >> li) | (pref << (32 - li))) : pref;
          b = (li + __ffs(rot) - 1) & 31;
        }
      }
      if (__ballot(want) == 0ull) break;
      bool win = false;
      if (want) {
        if (force) {
          win = true;                         // backstop; may conflict (rare)
        } else {
          atomicMax(&claim[w][hl][b], key);
          __builtin_amdgcn_wave_barrier();
          int cv = ((volatile int*)claim[w][hl])[b];
          if (cv == key) {
            win = true;
            ((volatile int*)claim[w][hl])[b] = 0x7FFFFFFF;  // lock for color
          } else {
            excl |= 1u << b;
          }
        }
      }
      __builtin_amdgcn_wave_barrier();
      if (win) { placed = true; myb = b; }
    }

    float v = 0.f; unsigned col = 0u;
    if (placed) {                             // consume lowest col of myb
      unsigned m16 = (unsigned)myocc[myb];
      int m = __ffs(m16) - 1;
      col = (unsigned)(myb + 32 * m);
      unsigned nm16 = m16 & (m16 - 1u);
      myocc[myb] = (unsigned short)nm16;
      int nm = __popc(nm16);
      unsigned bit = 1u << myb;
      bmAll = (nm >= 1) ? (bmAll | bit) : (bmAll & ~bit);
      bm2   = (nm >= 2) ? (bm2   | bit) : (bm2   & ~bit);
      bm4   = (nm >= 4) ? (bm4   | bit) : (bm4   & ~bit);
      v = wrow[col];
      --rem;
    }
    vals[c * NH + p] = v;                     // idle lanes write harmless 0
    offs[c * NH + p] = col;
    ++c;
  }
  if (lane == 0) cntw[w] = c;
  for (int e = c; e < PAD; ++e) {             // zero-fill tail slots
    vals[e * NH + p] = 0.f;
    offs[e * NH + p] = 0u;
  }
}

// ---------------------------------------------------------------------------
// DPP wave-64 sum reduction on the VALU pipe; lane 63 ends with the full sum.
// ---------------------------------------------------------------------------
template <int CTRL, int RM>
__device__ __forceinline__ float dppadd(float v) {
  int t = __builtin_amdgcn_update_dpp(0, __float_as_int(v), CTRL, RM, 0xF, true);
  return v + __int_as_float(t);
}
__device__ __forceinline__ float wave_sum_lane63(float v) {
  v = dppadd<0xB1,  0xF>(v);
  v = dppadd<0x4E,  0xF>(v);
  v = dppadd<0x141, 0xF>(v);
  v = dppadd<0x140, 0xF>(v);
  v = dppadd<0x142, 0xA>(v);
  v = dppadd<0x143, 0xC>(v);
  return v;
}

// fast tanh: (t-1)/(t+1), t = exp(2x), clamp |x|<=9.
__device__ __forceinline__ float ftanh(float x) {
  float xc = fminf(9.0f, fmaxf(-9.0f, x));
  float t  = __expf(2.0f * xc);
  return (t - 1.0f) * __builtin_amdgcn_rcpf(t + 1.0f);
}

// ---------------------------------------------------------------------------
// Main: one block per batch, 512 threads, 2048 sequential steps (x2 unroll).
// Round-13 kernel verbatim.
// ---------------------------------------------------------------------------
#define GA(T_RD, E) (*(const float*)((const char*)(T_RD) + cidx[E]))

#define ESN_STEP(T_RD, T_WR, RWR, SIDX)                                      \
  {                                                                          \
    float d0 = 0.f, d1 = 0.f, d2 = 0.f, d3 = 0.f;                            \
    _Pragma("unroll")                                                        \
    for (int e = 0; e < PAD; e += 8) {                                       \
      if (e < cw) {                                                          \
        d0 = fmaf(wval[e + 0], GA(T_RD, e + 0), d0);                         \
        d1 = fmaf(wval[e + 1], GA(T_RD, e + 1), d1);                         \
        d2 = fmaf(wval[e + 2], GA(T_RD, e + 2), d2);                         \
        d3 = fmaf(wval[e + 3], GA(T_RD, e + 3), d3);                         \
        d0 = fmaf(wval[e + 4], GA(T_RD, e + 4), d0);                         \
        d1 = fmaf(wval[e + 5], GA(T_RD, e + 5), d1);                         \
        d2 = fmaf(wval[e + 6], GA(T_RD, e + 6), d2);                         \
        d3 = fmaf(wval[e + 7], GA(T_RD, e + 7), d3);                         \
      }                                                                      \
    }                                                                        \
    float dot  = (d0 + d1) + (d2 + d3);                                      \
    float xp   = x_lds[SIDX] * w_ih;                                         \
    float dhdt = ((dot - h) + xp) + z_prev * w_zh;                           \
    float hn   = h + 0.1f * dhdt;                                            \
    float thn  = ftanh(hn);                                                  \
    T_WR[row] = thn;                                                         \
    oh[(SIDX) * NH + row] = hn;                                              \
    float pzs = wave_sum_lane63(thn * w_hz);                                 \
    if (lane == 63) red[RWR][wid] = pzs;                                     \
    asm volatile("s_waitcnt lgkmcnt(0)\n\ts_barrier" ::: "memory");          \
    float4 r0 = *(const float4*)&red[RWR][0];                                \
    float4 r1 = *(const float4*)&red[RWR][4];                                \
    float z = ((r0.x + r0.y) + (r0.z + r0.w)) + ((r1.x + r1.y) + (r1.z + r1.w)); \
    if (p == 0) oz[SIDX] = z;                                                \
    z_prev = z; h = hn;                                                      \
  }

__global__ __launch_bounds__(512, 2) void esn_steps(
    const float* __restrict__ x,   const float* __restrict__ h0,
    const float* __restrict__ Wih, const float* __restrict__ Whz,
    const float* __restrict__ Wzh, const float* __restrict__ vals,
    const unsigned* __restrict__ offs, const int* __restrict__ perm2,
    const int* __restrict__ cntw, float* __restrict__ out) {
  __shared__ float t_lds[2][NH];              // tanh(h), double-buffered
  __shared__ float x_lds[TT];                 // this batch's input row
  __shared__ __align__(16) float red[2][8];   // cross-wave partials for z

  const int p    = threadIdx.x;               // position owned
  const int b    = blockIdx.x;
  const int lane = p & 63;
  const int wid  = p >> 6;
  const int row  = perm2[p];                  // actual hidden unit

  float* t0 = t_lds[0];
  float* t1 = t_lds[1];

  for (int i = p; i < TT; i += NH) x_lds[i] = x[(size_t)b * TT + i];

  int cw = __builtin_amdgcn_readfirstlane((cntw[wid] + 7) & ~7);

  float    wval[PAD];
  unsigned cidx[PAD];
  #pragma unroll
  for (int e = 0; e < PAD; ++e) {
    wval[e] = vals[e * NH + p];
    cidx[e] = offs[e * NH + p] * 4u;
  }
  #pragma unroll
  for (int e = 0; e < PIN; ++e)
    asm volatile("" : "+v"(wval[e]), "+v"(cidx[e]));

  const float w_ih = Wih[row];
  const float w_hz = Whz[row];
  const float w_zh = Wzh[row];
  float h = h0[(size_t)b * NH + row];

  float* oz = out + (size_t)b * TT;                        // z region [B,T,1]
  float* oh = out + (size_t)BB * TT + (size_t)b * TT * NH; // h region [B,T,NH]

  float th0 = ftanh(h);
  t0[row] = th0;
  float pz = wave_sum_lane63(th0 * w_hz);
  if (lane == 63) red[0][wid] = pz;
  __syncthreads();
  float4 i0 = *(const float4*)&red[0][0];
  float4 i1 = *(const float4*)&red[0][4];
  float z_prev = ((i0.x + i0.y) + (i0.z + i0.w)) + ((i1.x + i1.y) + (i1.z + i1.w));

  for (int s = 0; s < TT; s += 2) {
    ESN_STEP(t0, t1, 1, s);
    ESN_STEP(t1, t0, 0, s + 1);
  }
}

// ---------------------------------------------------------------------------
extern "C" void kernel_launch(void* const* d_in, const int* in_sizes, int n_in,
                              void* d_out, int out_size, void* d_ws,
                              size_t ws_size, hipStream_t stream) {
  const float* x   = (const float*)d_in[0];
  const float* h0  = (const float*)d_in[1];
  const float* Wih = (const float*)d_in[2];
  const float* Whh = (const float*)d_in[3];
  const float* Whz = (const float*)d_in[4];
  const float* Wzh = (const float*)d_in[5];
  float* out = (float*)d_out;

  float*    vals  = (float*)d_ws;                    // PAD*NH f32 = 192 KB
  unsigned* offs  = (unsigned*)(vals + PAD * NH);    // PAD*NH u32 = 192 KB
  int*      nnz   = (int*)(offs + PAD * NH);         // NH
  int*      perm  = nnz + NH;                        // NH
  int*      perm2 = perm + NH;                       // NH
  int*      cntw  = perm2 + NH;                      // 8

  hipLaunchKernelGGL(count_nnz, dim3(NH / 8), dim3(512), 0, stream, Whh, nnz);
  hipLaunchKernelGGL(sort_rows, dim3(1), dim3(512), 0, stream, nnz, perm);
  hipLaunchKernelGGL(build_psched, dim3(1), dim3(512), 0, stream,
                     Whh, perm, perm2, vals, offs, cntw);
  hipLaunchKernelGGL(esn_steps, dim3(BB), dim3(512), 0, stream,
                     x, h0, Wih, Whz, Wzh, vals, offs, perm2, cntw, out);
}